// Round 4
// baseline (347.640 us; speedup 1.0000x reference)
//
#include <hip/hip_runtime.h>

// DecomposedAttention: out = Q (Q^T Q) (K^T V) Q^T / 64  per (b,h) slice.
// Shapes: 16 head-slices of [N=2048, D=64], fp32 in, fp32 out [16, N, N].
#define NTOK 2048
#define DDIM 64
#define NHEAD 16          // B*H = 2*8
#define SEG 32            // N-segments for partial Gram reductions
#define RPS (NTOK / SEG)  // 64 rows per segment

typedef float f32x4 __attribute__((ext_vector_type(4)));
typedef short bf16x8 __attribute__((ext_vector_type(8)));
typedef short short8 __attribute__((ext_vector_type(8)));
typedef unsigned short u16;

__device__ __forceinline__ u16 f2bf(float f) {
  union { float f; unsigned u; } v; v.f = f;
  unsigned u = v.u;
  return (u16)((u + 0x7fffu + ((u >> 16) & 1u)) >> 16);  // RNE, no NaN here
}

// ---------------------------------------------------------------------------
// Kernel A: per (head, segment) partial M1 = Q^T Q and M2 = K^T V  (64x64 each)
// grid (16, 32), block 256
__global__ __launch_bounds__(256) void k_partials(
    const float* __restrict__ Q, const float* __restrict__ Kp,
    const float* __restrict__ V, float* __restrict__ P1, float* __restrict__ P2) {
  const int h = blockIdx.x, s = blockIdx.y;
  const int t = threadIdx.x;
  const size_t base = (size_t)h * NTOK * DDIM + (size_t)s * RPS * DDIM;

  __shared__ float Qs[RPS][DDIM];  // 16 KB each, 48 KB total
  __shared__ float Ks[RPS][DDIM];
  __shared__ float Vs[RPS][DDIM];

  for (int i = t; i < RPS * DDIM / 4; i += 256) {
    ((float4*)Qs)[i] = ((const float4*)(Q + base))[i];
    ((float4*)Ks)[i] = ((const float4*)(Kp + base))[i];
    ((float4*)Vs)[i] = ((const float4*)(V + base))[i];
  }
  __syncthreads();

  const int i0 = (t & 15) * 4, j0 = (t >> 4) * 4;  // thread owns 4x4 of 64x64
  float m1[4][4] = {{0}}, m2[4][4] = {{0}};
  for (int n = 0; n < RPS; n++) {
    f32x4 qi = *(const f32x4*)&Qs[n][i0];
    f32x4 qj = *(const f32x4*)&Qs[n][j0];
    f32x4 ki = *(const f32x4*)&Ks[n][i0];
    f32x4 vj = *(const f32x4*)&Vs[n][j0];
#pragma unroll
    for (int a = 0; a < 4; a++)
#pragma unroll
      for (int b = 0; b < 4; b++) {
        m1[a][b] += qi[a] * qj[b];
        m2[a][b] += ki[a] * vj[b];
      }
  }
  float* p1 = P1 + (size_t)(h * SEG + s) * 4096;
  float* p2 = P2 + (size_t)(h * SEG + s) * 4096;
#pragma unroll
  for (int a = 0; a < 4; a++)
#pragma unroll
    for (int b = 0; b < 4; b++) {
      p1[(i0 + a) * 64 + j0 + b] = m1[a][b];
      p2[(i0 + a) * 64 + j0 + b] = m2[a][b];
    }
}

// ---------------------------------------------------------------------------
// Kernel B: parallel reduction of partials -> M1, M2.
// grid (16, 16) = 256 blocks, block 256; coalesced 1 KB/seg per block.
__global__ __launch_bounds__(256) void k_reduce(
    const float* __restrict__ P1, const float* __restrict__ P2,
    float* __restrict__ M1, float* __restrict__ M2) {
  const int h = blockIdx.x;
  const int e = blockIdx.y * 256 + threadIdx.x;  // element 0..4095
  const size_t base = (size_t)h * SEG * 4096 + e;
  float s1 = 0.f, s2 = 0.f;
#pragma unroll 8
  for (int s = 0; s < SEG; s++) {
    s1 += P1[base + (size_t)s * 4096];
    s2 += P2[base + (size_t)s * 4096];
  }
  M1[(size_t)h * 4096 + e] = s1;
  M2[(size_t)h * 4096 + e] = s2;
}

// ---------------------------------------------------------------------------
// Kernel C: per block, recompute M3 = M1 @ M2 (64x64, cheap, redundant x32),
// then T-strip = (Q_strip @ M3)/64 -> bf16, and Qb = bf16(Q_strip).
// grid (16, 32), block 256.
__global__ __launch_bounds__(256) void k_Tm3(
    const float* __restrict__ Q, const float* __restrict__ M1,
    const float* __restrict__ M2, u16* __restrict__ Tb, u16* __restrict__ Qb) {
  const int h = blockIdx.x, s = blockIdx.y, t = threadIdx.x;
  const size_t base = (size_t)h * NTOK * DDIM + (size_t)s * RPS * DDIM;

  __shared__ float M1s[64][65];  // pad 65: row-i scalar reads conflict-free
  __shared__ float M2s[64][64];  // row f32x4 broadcast reads
  __shared__ float M3s[64][68];  // pad 68: rows stay 16B-aligned for f32x4
  __shared__ float Qs[64][65];   // pad 65: column-ish reads conflict-free

  for (int i = t; i < 4096; i += 256) {
    M1s[i >> 6][i & 63] = M1[(size_t)h * 4096 + i];
    Qs[i >> 6][i & 63] = Q[base + i];
  }
  for (int i = t; i < 1024; i += 256)
    ((f32x4*)M2s)[i] = ((const f32x4*)(M2 + (size_t)h * 4096))[i];
  __syncthreads();

  // M3 = M1 @ M2 : thread (i, j0..j0+15)
  {
    const int i = t & 63, j0 = (t >> 6) * 16;
    float acc[16] = {0};
    for (int k = 0; k < 64; k++) {
      float a = M1s[i][k];
      f32x4 b0 = *(const f32x4*)&M2s[k][j0 + 0];
      f32x4 b1 = *(const f32x4*)&M2s[k][j0 + 4];
      f32x4 b2 = *(const f32x4*)&M2s[k][j0 + 8];
      f32x4 b3 = *(const f32x4*)&M2s[k][j0 + 12];
#pragma unroll
      for (int j = 0; j < 4; j++) {
        acc[j + 0] += a * b0[j];
        acc[j + 4] += a * b1[j];
        acc[j + 8] += a * b2[j];
        acc[j + 12] += a * b3[j];
      }
    }
#pragma unroll
    for (int j = 0; j < 16; j++) M3s[i][j0 + j] = acc[j];
  }
  __syncthreads();

  // T = (Q_strip @ M3)/64 : thread (row n, cols k0..k0+15)
  const int n = t & 63, k0 = (t >> 6) * 16;
  float acc[16] = {0};
  for (int d = 0; d < 64; d++) {
    float q = Qs[n][d];
    f32x4 b0 = *(const f32x4*)&M3s[d][k0 + 0];
    f32x4 b1 = *(const f32x4*)&M3s[d][k0 + 4];
    f32x4 b2 = *(const f32x4*)&M3s[d][k0 + 8];
    f32x4 b3 = *(const f32x4*)&M3s[d][k0 + 12];
#pragma unroll
    for (int j = 0; j < 4; j++) {
      acc[j + 0] += q * b0[j];
      acc[j + 4] += q * b1[j];
      acc[j + 8] += q * b2[j];
      acc[j + 12] += q * b3[j];
    }
  }
  const float inv = 1.0f / 64.0f;
  short8 tv0, tv1, qv0, qv1;
#pragma unroll
  for (int j = 0; j < 8; j++) {
    tv0[j] = (short)f2bf(acc[j] * inv);
    tv1[j] = (short)f2bf(acc[j + 8] * inv);
    qv0[j] = (short)f2bf(Qs[n][k0 + j]);
    qv1[j] = (short)f2bf(Qs[n][k0 + 8 + j]);
  }
  u16* tb = Tb + base + (size_t)n * DDIM + k0;
  u16* qb = Qb + base + (size_t)n * DDIM + k0;
  *(short8*)tb = tv0;
  *(short8*)(tb + 8) = tv1;
  *(short8*)qb = qv0;
  *(short8*)(qb + 8) = qv1;
}

// ---------------------------------------------------------------------------
// Kernel D: out[h] = Tb[h] @ Qb[h]^T  (N x N, K=64), bf16 MFMA, fp32 out.
// grid (16,16,16): (bcol, brow, head); block 256 = 4 waves, 128x128 tile.
// Epilogue: LDS transpose -> global_store_dwordx4 with NT (nontemporal)
// flag: output is write-once-never-read; bypassing L2 allocation keeps
// Tb/Qb operand tiles resident instead of being evicted by the 268 MB
// output stream.
#define TRS 68  // padded LDS row stride (dwords) for the transpose buffer
__global__ __launch_bounds__(256) void k_gemm(
    const u16* __restrict__ Tb, const u16* __restrict__ Qb,
    float* __restrict__ out) {
  const int h = blockIdx.z;
  const int brow = blockIdx.y * 128, bcol = blockIdx.x * 128;
  const int t = threadIdx.x, w = t >> 6, l = t & 63;
  const int wr = w >> 1, wc = w & 1;  // 2x2 waves, 64x64 each
  const int lr = l & 15, lk = l >> 4; // frag row, k-group

  const u16* Th = Tb + (size_t)h * NTOK * DDIM;
  const u16* Qh = Qb + (size_t)h * NTOK * DDIM;

  bf16x8 a[4][2];
#pragma unroll
  for (int mi = 0; mi < 4; mi++) {
    const int row = brow + wr * 64 + mi * 16 + lr;
    const u16* p = Th + (size_t)row * DDIM + lk * 8;
    a[mi][0] = *(const bf16x8*)p;
    a[mi][1] = *(const bf16x8*)(p + 32);
  }

  f32x4 acc[4][4] = {};
#pragma unroll
  for (int ni = 0; ni < 4; ni++) {
    const int col = bcol + wc * 64 + ni * 16 + lr;
    const u16* p = Qh + (size_t)col * DDIM + lk * 8;
    bf16x8 b0 = *(const bf16x8*)p;
    bf16x8 b1 = *(const bf16x8*)(p + 32);
#pragma unroll
    for (int mi = 0; mi < 4; mi++) {
      acc[mi][ni] = __builtin_amdgcn_mfma_f32_16x16x32_bf16(a[mi][0], b0, acc[mi][ni], 0, 0, 0);
      acc[mi][ni] = __builtin_amdgcn_mfma_f32_16x16x32_bf16(a[mi][1], b1, acc[mi][ni], 0, 0, 0);
    }
  }

  // ---- transposed epilogue ----
  __shared__ float tr[4][16 * TRS];  // per-wave 16x64 slab, padded
  float* wbuf = tr[w];
  const int rrow = l >> 2;   // 0..15: local row this lane stores
  const int rchk = l & 3;    // 0..3 : which 16-col group

  float* oh = out + (size_t)h * NTOK * NTOK;
#pragma unroll
  for (int mi = 0; mi < 4; mi++) {
    // scatter acc[mi] into LDS: local row = lk*4+reg, col = ni*16+lr
#pragma unroll
    for (int ni = 0; ni < 4; ni++)
#pragma unroll
      for (int reg = 0; reg < 4; reg++)
        wbuf[(lk * 4 + reg) * TRS + ni * 16 + lr] = acc[mi][ni][reg];
    __syncthreads();
    // gather rows as f32x4, store fully-coalesced NT dwordx4
    const int gr = brow + wr * 64 + mi * 16 + rrow;
    float* orow = oh + (size_t)gr * NTOK + bcol + wc * 64;
#pragma unroll
    for (int j = 0; j < 4; j++) {
      f32x4 vv = *(const f32x4*)&wbuf[rrow * TRS + rchk * 4 + 16 * j];
      __builtin_nontemporal_store(vv, (f32x4*)&orow[rchk * 4 + 16 * j]);
    }
    __syncthreads();  // protect WAR before next mi reuses the buffer
  }
}

// ---------------------------------------------------------------------------
extern "C" void kernel_launch(void* const* d_in, const int* in_sizes, int n_in,
                              void* d_out, int out_size, void* d_ws, size_t ws_size,
                              hipStream_t stream) {
  // inputs: X (dead), Q, K, V — each [2,8,2048,64] fp32
  const float* Q = (const float*)d_in[1];
  const float* K = (const float*)d_in[2];
  const float* V = (const float*)d_in[3];
  float* out = (float*)d_out;

  // workspace layout (~25 MB)
  char* ws = (char*)d_ws;
  float* P1 = (float*)(ws);                      // 16*32*4096 f32 = 8 MB
  float* P2 = (float*)(ws + (8u << 20));         // 8 MB
  float* M1 = (float*)(ws + (16u << 20));        // 16*4096 f32 = 256 KB
  float* M2 = (float*)(ws + (16u << 20) + (256u << 10));  // 256 KB
  u16* Tb   = (u16*)(ws + (17u << 20));          // 16*2048*64 bf16 = 4 MB
  u16* Qb   = (u16*)(ws + (21u << 20));          // 4 MB

  k_partials<<<dim3(NHEAD, SEG), 256, 0, stream>>>(Q, K, V, P1, P2);
  k_reduce<<<dim3(NHEAD, 16), 256, 0, stream>>>(P1, P2, M1, M2);
  k_Tm3<<<dim3(NHEAD, SEG), 256, 0, stream>>>(Q, M1, M2, Tb, Qb);
  k_gemm<<<dim3(NTOK / 128, NTOK / 128, NHEAD), 256, 0, stream>>>(Tb, Qb, out);
}

// Round 5
// 330.051 us; speedup vs baseline: 1.0533x; 1.0533x over previous
//
#include <hip/hip_runtime.h>

// DecomposedAttention: out = Q (Q^T Q) (K^T V) Q^T / 64  per (b,h) slice.
// Shapes: 16 head-slices of [N=2048, D=64], fp32 in, fp32 out [16, N, N].
// Final structure: 4 dispatches; k_gemm is write-bound (268 MB fp32 output,
// floor ~43 us @ 6.3 TB/s). Epilogue variants (scalar / LDS-transpose /
// NT) measured equal within noise; keeping the simplest (scalar dword,
// 4x64B segments per wave-instruction).
#define NTOK 2048
#define DDIM 64
#define NHEAD 16          // B*H = 2*8
#define SEG 32            // N-segments for partial Gram reductions
#define RPS (NTOK / SEG)  // 64 rows per segment

typedef float f32x4 __attribute__((ext_vector_type(4)));
typedef short bf16x8 __attribute__((ext_vector_type(8)));
typedef short short8 __attribute__((ext_vector_type(8)));
typedef unsigned short u16;

__device__ __forceinline__ u16 f2bf(float f) {
  union { float f; unsigned u; } v; v.f = f;
  unsigned u = v.u;
  return (u16)((u + 0x7fffu + ((u >> 16) & 1u)) >> 16);  // RNE, no NaN here
}

// ---------------------------------------------------------------------------
// Kernel A: per (head, segment) partial M1 = Q^T Q and M2 = K^T V  (64x64 each)
// grid (16, 32), block 256
__global__ __launch_bounds__(256) void k_partials(
    const float* __restrict__ Q, const float* __restrict__ Kp,
    const float* __restrict__ V, float* __restrict__ P1, float* __restrict__ P2) {
  const int h = blockIdx.x, s = blockIdx.y;
  const int t = threadIdx.x;
  const size_t base = (size_t)h * NTOK * DDIM + (size_t)s * RPS * DDIM;

  __shared__ float Qs[RPS][DDIM];  // 16 KB each, 48 KB total
  __shared__ float Ks[RPS][DDIM];
  __shared__ float Vs[RPS][DDIM];

  for (int i = t; i < RPS * DDIM / 4; i += 256) {
    ((float4*)Qs)[i] = ((const float4*)(Q + base))[i];
    ((float4*)Ks)[i] = ((const float4*)(Kp + base))[i];
    ((float4*)Vs)[i] = ((const float4*)(V + base))[i];
  }
  __syncthreads();

  const int i0 = (t & 15) * 4, j0 = (t >> 4) * 4;  // thread owns 4x4 of 64x64
  float m1[4][4] = {{0}}, m2[4][4] = {{0}};
  for (int n = 0; n < RPS; n++) {
    f32x4 qi = *(const f32x4*)&Qs[n][i0];
    f32x4 qj = *(const f32x4*)&Qs[n][j0];
    f32x4 ki = *(const f32x4*)&Ks[n][i0];
    f32x4 vj = *(const f32x4*)&Vs[n][j0];
#pragma unroll
    for (int a = 0; a < 4; a++)
#pragma unroll
      for (int b = 0; b < 4; b++) {
        m1[a][b] += qi[a] * qj[b];
        m2[a][b] += ki[a] * vj[b];
      }
  }
  float* p1 = P1 + (size_t)(h * SEG + s) * 4096;
  float* p2 = P2 + (size_t)(h * SEG + s) * 4096;
#pragma unroll
  for (int a = 0; a < 4; a++)
#pragma unroll
    for (int b = 0; b < 4; b++) {
      p1[(i0 + a) * 64 + j0 + b] = m1[a][b];
      p2[(i0 + a) * 64 + j0 + b] = m2[a][b];
    }
}

// ---------------------------------------------------------------------------
// Kernel B: parallel reduction of partials -> M1, M2.
// grid (16, 16) = 256 blocks, block 256; coalesced 1 KB/seg per block.
__global__ __launch_bounds__(256) void k_reduce(
    const float* __restrict__ P1, const float* __restrict__ P2,
    float* __restrict__ M1, float* __restrict__ M2) {
  const int h = blockIdx.x;
  const int e = blockIdx.y * 256 + threadIdx.x;  // element 0..4095
  const size_t base = (size_t)h * SEG * 4096 + e;
  float s1 = 0.f, s2 = 0.f;
#pragma unroll 8
  for (int s = 0; s < SEG; s++) {
    s1 += P1[base + (size_t)s * 4096];
    s2 += P2[base + (size_t)s * 4096];
  }
  M1[(size_t)h * 4096 + e] = s1;
  M2[(size_t)h * 4096 + e] = s2;
}

// ---------------------------------------------------------------------------
// Kernel C: per block, recompute M3 = M1 @ M2 (64x64, cheap, redundant x32),
// then T-strip = (Q_strip @ M3)/64 -> bf16, and Qb = bf16(Q_strip).
// grid (16, 32), block 256.
__global__ __launch_bounds__(256) void k_Tm3(
    const float* __restrict__ Q, const float* __restrict__ M1,
    const float* __restrict__ M2, u16* __restrict__ Tb, u16* __restrict__ Qb) {
  const int h = blockIdx.x, s = blockIdx.y, t = threadIdx.x;
  const size_t base = (size_t)h * NTOK * DDIM + (size_t)s * RPS * DDIM;

  __shared__ float M1s[64][65];  // pad 65: row-i scalar reads conflict-free
  __shared__ float M2s[64][64];  // row f32x4 broadcast reads
  __shared__ float M3s[64][68];  // pad 68: rows stay 16B-aligned for f32x4
  __shared__ float Qs[64][65];   // pad 65: column-ish reads conflict-free

  for (int i = t; i < 4096; i += 256) {
    M1s[i >> 6][i & 63] = M1[(size_t)h * 4096 + i];
    Qs[i >> 6][i & 63] = Q[base + i];
  }
  for (int i = t; i < 1024; i += 256)
    ((f32x4*)M2s)[i] = ((const f32x4*)(M2 + (size_t)h * 4096))[i];
  __syncthreads();

  // M3 = M1 @ M2 : thread (i, j0..j0+15)
  {
    const int i = t & 63, j0 = (t >> 6) * 16;
    float acc[16] = {0};
    for (int k = 0; k < 64; k++) {
      float a = M1s[i][k];
      f32x4 b0 = *(const f32x4*)&M2s[k][j0 + 0];
      f32x4 b1 = *(const f32x4*)&M2s[k][j0 + 4];
      f32x4 b2 = *(const f32x4*)&M2s[k][j0 + 8];
      f32x4 b3 = *(const f32x4*)&M2s[k][j0 + 12];
#pragma unroll
      for (int j = 0; j < 4; j++) {
        acc[j + 0] += a * b0[j];
        acc[j + 4] += a * b1[j];
        acc[j + 8] += a * b2[j];
        acc[j + 12] += a * b3[j];
      }
    }
#pragma unroll
    for (int j = 0; j < 16; j++) M3s[i][j0 + j] = acc[j];
  }
  __syncthreads();

  // T = (Q_strip @ M3)/64 : thread (row n, cols k0..k0+15)
  const int n = t & 63, k0 = (t >> 6) * 16;
  float acc[16] = {0};
  for (int d = 0; d < 64; d++) {
    float q = Qs[n][d];
    f32x4 b0 = *(const f32x4*)&M3s[d][k0 + 0];
    f32x4 b1 = *(const f32x4*)&M3s[d][k0 + 4];
    f32x4 b2 = *(const f32x4*)&M3s[d][k0 + 8];
    f32x4 b3 = *(const f32x4*)&M3s[d][k0 + 12];
#pragma unroll
    for (int j = 0; j < 4; j++) {
      acc[j + 0] += q * b0[j];
      acc[j + 4] += q * b1[j];
      acc[j + 8] += q * b2[j];
      acc[j + 12] += q * b3[j];
    }
  }
  const float inv = 1.0f / 64.0f;
  short8 tv0, tv1, qv0, qv1;
#pragma unroll
  for (int j = 0; j < 8; j++) {
    tv0[j] = (short)f2bf(acc[j] * inv);
    tv1[j] = (short)f2bf(acc[j + 8] * inv);
    qv0[j] = (short)f2bf(Qs[n][k0 + j]);
    qv1[j] = (short)f2bf(Qs[n][k0 + 8 + j]);
  }
  u16* tb = Tb + base + (size_t)n * DDIM + k0;
  u16* qb = Qb + base + (size_t)n * DDIM + k0;
  *(short8*)tb = tv0;
  *(short8*)(tb + 8) = tv1;
  *(short8*)qb = qv0;
  *(short8*)(qb + 8) = qv1;
}

// ---------------------------------------------------------------------------
// Kernel D: out[h] = Tb[h] @ Qb[h]^T  (N x N, K=64), bf16 MFMA, fp32 out.
// grid (16,16,16): (bcol, brow, head); block 256 = 4 waves, 128x128 tile.
// Write-bound: stores are 4x64B segments per wave-instruction (measured
// equal to LDS-transposed dwordx4 and NT variants).
__global__ __launch_bounds__(256) void k_gemm(
    const u16* __restrict__ Tb, const u16* __restrict__ Qb,
    float* __restrict__ out) {
  const int h = blockIdx.z;
  const int brow = blockIdx.y * 128, bcol = blockIdx.x * 128;
  const int t = threadIdx.x, w = t >> 6, l = t & 63;
  const int wr = w >> 1, wc = w & 1;  // 2x2 waves, 64x64 each
  const int lr = l & 15, lk = l >> 4; // frag row, k-group

  const u16* Th = Tb + (size_t)h * NTOK * DDIM;
  const u16* Qh = Qb + (size_t)h * NTOK * DDIM;

  bf16x8 a[4][2];
#pragma unroll
  for (int mi = 0; mi < 4; mi++) {
    const int row = brow + wr * 64 + mi * 16 + lr;
    const u16* p = Th + (size_t)row * DDIM + lk * 8;
    a[mi][0] = *(const bf16x8*)p;
    a[mi][1] = *(const bf16x8*)(p + 32);
  }

  f32x4 acc[4][4] = {};
#pragma unroll
  for (int ni = 0; ni < 4; ni++) {
    const int col = bcol + wc * 64 + ni * 16 + lr;
    const u16* p = Qh + (size_t)col * DDIM + lk * 8;
    bf16x8 b0 = *(const bf16x8*)p;
    bf16x8 b1 = *(const bf16x8*)(p + 32);
#pragma unroll
    for (int mi = 0; mi < 4; mi++) {
      acc[mi][ni] = __builtin_amdgcn_mfma_f32_16x16x32_bf16(a[mi][0], b0, acc[mi][ni], 0, 0, 0);
      acc[mi][ni] = __builtin_amdgcn_mfma_f32_16x16x32_bf16(a[mi][1], b1, acc[mi][ni], 0, 0, 0);
    }
  }

  float* oh = out + (size_t)h * NTOK * NTOK;
#pragma unroll
  for (int mi = 0; mi < 4; mi++)
#pragma unroll
    for (int ni = 0; ni < 4; ni++) {
      const int r0 = brow + wr * 64 + mi * 16 + lk * 4;
      const int c = bcol + wc * 64 + ni * 16 + lr;
#pragma unroll
      for (int reg = 0; reg < 4; reg++)
        oh[(size_t)(r0 + reg) * NTOK + c] = acc[mi][ni][reg];
    }
}

// ---------------------------------------------------------------------------
extern "C" void kernel_launch(void* const* d_in, const int* in_sizes, int n_in,
                              void* d_out, int out_size, void* d_ws, size_t ws_size,
                              hipStream_t stream) {
  // inputs: X (dead), Q, K, V — each [2,8,2048,64] fp32
  const float* Q = (const float*)d_in[1];
  const float* K = (const float*)d_in[2];
  const float* V = (const float*)d_in[3];
  float* out = (float*)d_out;

  // workspace layout (~25 MB)
  char* ws = (char*)d_ws;
  float* P1 = (float*)(ws);                      // 16*32*4096 f32 = 8 MB
  float* P2 = (float*)(ws + (8u << 20));         // 8 MB
  float* M1 = (float*)(ws + (16u << 20));        // 16*4096 f32 = 256 KB
  float* M2 = (float*)(ws + (16u << 20) + (256u << 10));  // 256 KB
  u16* Tb   = (u16*)(ws + (17u << 20));          // 16*2048*64 bf16 = 4 MB
  u16* Qb   = (u16*)(ws + (21u << 20));          // 4 MB

  k_partials<<<dim3(NHEAD, SEG), 256, 0, stream>>>(Q, K, V, P1, P2);
  k_reduce<<<dim3(NHEAD, 16), 256, 0, stream>>>(P1, P2, M1, M2);
  k_Tm3<<<dim3(NHEAD, SEG), 256, 0, stream>>>(Q, M1, M2, Tb, Qb);
  k_gemm<<<dim3(NTOK / 128, NTOK / 128, NHEAD), 256, 0, stream>>>(Tb, Qb, out);
}